// Round 1
// baseline (432.205 us; speedup 1.0000x reference)
//
#include <hip/hip_runtime.h>
#include <hip/hip_bf16.h>

// Problem: x (B=256, R=1024, C=1024) fp32. rows/cols are N_IDX=64 int32 index
// vectors. Output = x everywhere, except at (b, rows[i], cols[j]) for all
// b, i, j, where it is "mute_msb(x)":
//   frexp: x = m * 2^e, m in [0.5, 1).  If e > 0 -> x * 2^-e = m (signed),
//   else identity.  In IEEE754 bits: if biased exponent E in [127, 255)
//   (|x| >= 1.0, finite), set exponent field to 126 keeping sign+mantissa;
//   else (subnormal/zero/|x|<1/inf/nan) identity.
//
// Strategy: bulk D2D copy (memory-bound, ~2.1 GB HBM traffic), then a small
// scatter-fixup kernel over B*nr*nc = ~1M elements (~0.4% of data).

#define RR 1024
#define CC 1024

__global__ void mute_fixup_kernel(const float* __restrict__ x,
                                  const int* __restrict__ rows,
                                  const int* __restrict__ cols,
                                  float* __restrict__ out,
                                  int B, int nr, int nc) {
    int idx = blockIdx.x * blockDim.x + threadIdx.x;
    int total = B * nr * nc;
    if (idx >= total) return;

    int j = idx % nc;          // fastest: column index -> coalesced for arange cols
    int t = idx / nc;
    int i = t % nr;
    int b = t / nr;

    int r = rows[i];
    int c = cols[j];

    size_t off = (size_t)b * (RR * CC) + (size_t)r * CC + (size_t)c;
    float v = x[off];

    unsigned u = __float_as_uint(v);
    unsigned E = (u >> 23) & 0xffu;
    float res = v;
    if (E >= 127u && E < 255u) {
        // exponent field -> 126: value becomes signed mantissa in [0.5, 1)
        res = __uint_as_float((u & 0x807fffffu) | (126u << 23));
    }
    out[off] = res;
}

extern "C" void kernel_launch(void* const* d_in, const int* in_sizes, int n_in,
                              void* d_out, int out_size, void* d_ws, size_t ws_size,
                              hipStream_t stream) {
    const float* x   = (const float*)d_in[0];
    const int* rows  = (const int*)d_in[1];
    const int* cols  = (const int*)d_in[2];
    float* out       = (float*)d_out;

    const int nr = in_sizes[1];
    const int nc = in_sizes[2];
    const int B  = in_sizes[0] / (RR * CC);

    // Bulk copy: out = x  (graph-capturable async d2d copy)
    hipMemcpyAsync(out, x, (size_t)in_sizes[0] * sizeof(float),
                   hipMemcpyDeviceToDevice, stream);

    // Fixup the (rows x cols) grid per batch plane.
    int total = B * nr * nc;
    int block = 256;
    int grid = (total + block - 1) / block;
    mute_fixup_kernel<<<grid, block, 0, stream>>>(x, rows, cols, out, B, nr, nc);
}